// Round 3
// baseline (445.361 us; speedup 1.0000x reference)
//
#include <hip/hip_runtime.h>
#include <hip/hip_bf16.h>

#define NLAYER 4
#define DDIM 256
#define TSEQ 4096
#define NBATCH 8
#define MROWS (NBATCH * TSEQ)   // 32768
#define CLEN 32                 // chunk length for parallel scan
#define NCHUNK (TSEQ / CLEN)    // 128

typedef float f32x4 __attribute__((ext_vector_type(4)));
typedef short bf16x8 __attribute__((ext_vector_type(8)));

__device__ __forceinline__ float bf2f(unsigned short u) {
    union { unsigned int i; float f; } v; v.i = ((unsigned int)u) << 16; return v.f;
}
__device__ __forceinline__ unsigned short f2bf(float f) {
    union { float f; unsigned int i; } v; v.f = f;
    unsigned int r = v.i + 0x7fffu + ((v.i >> 16) & 1u);
    return (unsigned short)(r >> 16);
}

// async global->LDS, 16B per lane; lds base must be wave-uniform (HW adds lane*16)
__device__ __forceinline__ void gload16(const unsigned short* g, unsigned short* l) {
    __builtin_amdgcn_global_load_lds(
        (const __attribute__((address_space(1))) unsigned int*)g,
        (__attribute__((address_space(3))) unsigned int*)l, 16, 0, 0);
}

// ---------------- prepack: weights -> bf16 (gamma folded into B, -C_im), lambda, lambda^CLEN ----
__global__ __launch_bounds__(256) void prepack_kernel(
    const float* __restrict__ nu_log, const float* __restrict__ theta_log,
    const float* __restrict__ gamma_log,
    const float* __restrict__ B_re, const float* __restrict__ B_im,
    const float* __restrict__ C_re, const float* __restrict__ C_im,
    const float* __restrict__ Wg,
    unsigned short* __restrict__ wBre, unsigned short* __restrict__ wBim,
    unsigned short* __restrict__ wWg, unsigned short* __restrict__ wCre,
    unsigned short* __restrict__ wCimn,
    float* __restrict__ lam_re, float* __restrict__ lam_im,
    float* __restrict__ lamC_re, float* __restrict__ lamC_im)
{
    int idx = blockIdx.x * 256 + threadIdx.x;
    const int total = NLAYER * DDIM * DDIM;
    if (idx < total) {
        int l = idx >> 16;
        int e = (idx >> 8) & 255;
        float gam = expf(gamma_log[l * DDIM + e]);
        wBre[idx]  = f2bf(B_re[idx] * gam);
        wBim[idx]  = f2bf(B_im[idx] * gam);
        wWg[idx]   = f2bf(Wg[idx]);
        wCre[idx]  = f2bf(C_re[idx]);
        wCimn[idx] = f2bf(-C_im[idx]);
    }
    if (idx < NLAYER * DDIM) {
        float mag = expf(-expf(nu_log[idx]));
        float th  = expf(theta_log[idx]);
        float ar = mag * cosf(th);
        float ai = mag * sinf(th);
        lam_re[idx] = ar;
        lam_im[idx] = ai;
        #pragma unroll
        for (int s = 0; s < 5; ++s) {   // lambda^32
            float nr = ar * ar - ai * ai;
            float ni = 2.0f * ar * ai;
            ar = nr; ai = ni;
        }
        lamC_re[idx] = ar;
        lamC_im[idx] = ai;
    }
}

// ---------------- LayerNorm: one wave per row (D=256), 4 rows/block ----------------
__global__ __launch_bounds__(256) void ln_kernel(
    const float* __restrict__ u, unsigned short* __restrict__ z,
    const float* __restrict__ scale, const float* __restrict__ bias)
{
    int wid = threadIdx.x >> 6;
    int lane = threadIdx.x & 63;
    int row = blockIdx.x * 4 + wid;
    const float4 v = *reinterpret_cast<const float4*>(u + (size_t)row * DDIM + lane * 4);
    float s  = v.x + v.y + v.z + v.w;
    float s2 = v.x * v.x + v.y * v.y + v.z * v.z + v.w * v.w;
    #pragma unroll
    for (int off = 32; off > 0; off >>= 1) {
        s  += __shfl_xor(s, off);
        s2 += __shfl_xor(s2, off);
    }
    float mu  = s * (1.0f / DDIM);
    float var = s2 * (1.0f / DDIM) - mu * mu;
    float inv = rsqrtf(var + 1e-5f);
    float zv[4] = { v.x, v.y, v.z, v.w };
    ushort4 o;
    unsigned short* op = (unsigned short*)&o;
    #pragma unroll
    for (int j = 0; j < 4; ++j) {
        int d = lane * 4 + j;
        op[j] = f2bf((zv[j] - mu) * inv * scale[d] + bias[d]);
    }
    *reinterpret_cast<ushort4*>(z + (size_t)row * DDIM + lane * 4) = o;
}

// ---------------- GEMM1 (fused 3-matrix): z x {Bre,Bim,Wg}^T -> bure, buim, sigmoid(g) ----------
// grid (4, 256): n0 = bx*64, m0 = by*128. BM=128, BN=64, BK=64, 4 waves (2x2).
// LDS linear, global source pre-swizzled (chunk ^= row&7), ds_read swizzled to match.
__global__ __launch_bounds__(256) void gemm1_kernel(
    const unsigned short* __restrict__ z,
    const unsigned short* __restrict__ wBre, const unsigned short* __restrict__ wBim,
    const unsigned short* __restrict__ wWg,
    unsigned short* __restrict__ bure, unsigned short* __restrict__ buim,
    unsigned short* __restrict__ sg)
{
    const int n0 = blockIdx.x * 64;
    const int m0 = blockIdx.y * 128;

    __shared__ unsigned short Al[128 * 64];      // 16 KB
    __shared__ unsigned short Wl[3][64 * 64];    // 24 KB

    const int tid = threadIdx.x;
    const int lane = tid & 63;
    const int wid = tid >> 6;
    const int wr = wid >> 1, wc = wid & 1;
    const int lr = lane >> 3;      // row within 8-row segment
    const int lc = lane & 7;       // 16B chunk within row

    const unsigned short* Wsrc0 = wBre;
    const unsigned short* Wsrc1 = wBim;
    const unsigned short* Wsrc2 = wWg;

    f32x4 acc[3][4][2] = {};

    for (int ko = 0; ko < 256; ko += 64) {
        // stage A: 16 segments of 1KB (8 rows x 128B); wave handles 4
        #pragma unroll
        for (int it = 0; it < 4; ++it) {
            int s = wid * 4 + it;
            int r = s * 8 + lr;
            int gc = lc ^ (r & 7);
            gload16(z + (size_t)(m0 + r) * 256 + ko + gc * 8, &Al[s * 512]);
        }
        // stage W tiles: 8 segments each; wave handles 2 per matrix
        #pragma unroll
        for (int it = 0; it < 2; ++it) {
            int s = wid * 2 + it;
            int r = s * 8 + lr;
            int gc = lc ^ (r & 7);
            size_t off = (size_t)(n0 + r) * 256 + ko + gc * 8;
            gload16(Wsrc0 + off, &Wl[0][s * 512]);
            gload16(Wsrc1 + off, &Wl[1][s * 512]);
            gload16(Wsrc2 + off, &Wl[2][s * 512]);
        }
        __syncthreads();   // drains vmcnt -> LDS visible

        #pragma unroll
        for (int k2 = 0; k2 < 64; k2 += 32) {
            int ac = (k2 >> 3) + (lane >> 4);     // logical 16B chunk
            bf16x8 a[4];
            #pragma unroll
            for (int mi = 0; mi < 4; ++mi) {
                int ar = wr * 64 + mi * 16 + (lane & 15);
                a[mi] = *reinterpret_cast<const bf16x8*>(&Al[ar * 64 + ((ac ^ (ar & 7)) * 8)]);
            }
            int br0 = wc * 32 + (lane & 15);
            int br1 = br0 + 16;
            #pragma unroll
            for (int mat = 0; mat < 3; ++mat) {
                bf16x8 b0 = *reinterpret_cast<const bf16x8*>(&Wl[mat][br0 * 64 + ((ac ^ (br0 & 7)) * 8)]);
                bf16x8 b1 = *reinterpret_cast<const bf16x8*>(&Wl[mat][br1 * 64 + ((ac ^ (br1 & 7)) * 8)]);
                #pragma unroll
                for (int mi = 0; mi < 4; ++mi) {
                    acc[mat][mi][0] = __builtin_amdgcn_mfma_f32_16x16x32_bf16(a[mi], b0, acc[mat][mi][0], 0, 0, 0);
                    acc[mat][mi][1] = __builtin_amdgcn_mfma_f32_16x16x32_bf16(a[mi], b1, acc[mat][mi][1], 0, 0, 0);
                }
            }
        }
        __syncthreads();   // protect LDS before restage
    }

    #pragma unroll
    for (int mat = 0; mat < 3; ++mat) {
        unsigned short* out = (mat == 0) ? bure : ((mat == 1) ? buim : sg);
        #pragma unroll
        for (int mi = 0; mi < 4; ++mi) {
            #pragma unroll
            for (int ni = 0; ni < 2; ++ni) {
                int col = n0 + wc * 32 + ni * 16 + (lane & 15);
                int mrow = m0 + wr * 64 + mi * 16 + (lane >> 4) * 4;
                #pragma unroll
                for (int j = 0; j < 4; ++j) {
                    float v = acc[mat][mi][ni][j];
                    if (mat == 2) v = 1.0f / (1.0f + expf(-v));
                    out[(size_t)(mrow + j) * 256 + col] = f2bf(v);
                }
            }
        }
    }
}

// ---------------- scan phase A: per-chunk local scan, write chunk finals (f32) -----------------
// 256 blocks x 256 threads; 4 chunks/block, 64 lanes/chunk, 4 d per lane (ushort4 loads)
__global__ __launch_bounds__(256) void scan_finals_kernel(
    const unsigned short* __restrict__ re, const unsigned short* __restrict__ im,
    float* __restrict__ fin_re, float* __restrict__ fin_im,
    const float* __restrict__ lam_re, const float* __restrict__ lam_im)
{
    const int lane = threadIdx.x & 63;
    const int chunk = blockIdx.x * 4 + (threadIdx.x >> 6);
    const int b = chunk >> 7;
    const int c = chunk & (NCHUNK - 1);
    const int d0 = lane * 4;
    const float4 l_re = *reinterpret_cast<const float4*>(lam_re + d0);
    const float4 l_im = *reinterpret_cast<const float4*>(lam_im + d0);
    const float lr[4] = { l_re.x, l_re.y, l_re.z, l_re.w };
    const float li[4] = { l_im.x, l_im.y, l_im.z, l_im.w };
    size_t base = ((size_t)b * TSEQ + (size_t)c * CLEN) * DDIM + d0;
    float hr[4] = {}, hi[4] = {};
    for (int k = 0; k < CLEN; ++k) {
        ushort4 vr = *reinterpret_cast<const ushort4*>(re + base + (size_t)k * DDIM);
        ushort4 vi = *reinterpret_cast<const ushort4*>(im + base + (size_t)k * DDIM);
        const unsigned short* pr = (const unsigned short*)&vr;
        const unsigned short* pi = (const unsigned short*)&vi;
        #pragma unroll
        for (int j = 0; j < 4; ++j) {
            float br = bf2f(pr[j]), bi = bf2f(pi[j]);
            float nr = fmaf(lr[j], hr[j], fmaf(-li[j], hi[j], br));
            float ni = fmaf(lr[j], hi[j], fmaf(li[j], hr[j], bi));
            hr[j] = nr; hi[j] = ni;
        }
    }
    float4 outr = { hr[0], hr[1], hr[2], hr[3] };
    float4 outi = { hi[0], hi[1], hi[2], hi[3] };
    *reinterpret_cast<float4*>(fin_re + (size_t)chunk * DDIM + d0) = outr;
    *reinterpret_cast<float4*>(fin_im + (size_t)chunk * DDIM + d0) = outi;
}

// ---------------- scan phase B: exclusive prefix across chunks; 8 blocks x 64 threads ----------
__global__ __launch_bounds__(64) void scan_prefix_kernel(
    const float* __restrict__ fin_re, const float* __restrict__ fin_im,
    float* __restrict__ pre_re, float* __restrict__ pre_im,
    const float* __restrict__ lamC_re, const float* __restrict__ lamC_im)
{
    const int d0 = threadIdx.x * 4;
    const int b = blockIdx.x;
    const float4 L_re = *reinterpret_cast<const float4*>(lamC_re + d0);
    const float4 L_im = *reinterpret_cast<const float4*>(lamC_im + d0);
    const float Lr[4] = { L_re.x, L_re.y, L_re.z, L_re.w };
    const float Li[4] = { L_im.x, L_im.y, L_im.z, L_im.w };
    float pr[4] = {}, pi[4] = {};
    for (int c = 0; c < NCHUNK; ++c) {
        size_t idx = ((size_t)b * NCHUNK + c) * DDIM + d0;
        float4 opr = { pr[0], pr[1], pr[2], pr[3] };
        float4 opi = { pi[0], pi[1], pi[2], pi[3] };
        *reinterpret_cast<float4*>(pre_re + idx) = opr;
        *reinterpret_cast<float4*>(pre_im + idx) = opi;
        float4 fr4 = *reinterpret_cast<const float4*>(fin_re + idx);
        float4 fi4 = *reinterpret_cast<const float4*>(fin_im + idx);
        const float* fr = (const float*)&fr4;
        const float* fi = (const float*)&fi4;
        #pragma unroll
        for (int j = 0; j < 4; ++j) {
            float nr = fmaf(Lr[j], pr[j], fmaf(-Li[j], pi[j], fr[j]));
            float ni = fmaf(Lr[j], pi[j], fmaf(Li[j], pr[j], fi[j]));
            pr[j] = nr; pi[j] = ni;
        }
    }
}

// ---------------- scan phase C: seeded re-scan, store bf16 in place ----------------------------
__global__ __launch_bounds__(256) void scan_apply_kernel(
    unsigned short* __restrict__ re, unsigned short* __restrict__ im,
    const float* __restrict__ pre_re, const float* __restrict__ pre_im,
    const float* __restrict__ lam_re, const float* __restrict__ lam_im)
{
    const int lane = threadIdx.x & 63;
    const int chunk = blockIdx.x * 4 + (threadIdx.x >> 6);
    const int b = chunk >> 7;
    const int c = chunk & (NCHUNK - 1);
    const int d0 = lane * 4;
    const float4 l_re = *reinterpret_cast<const float4*>(lam_re + d0);
    const float4 l_im = *reinterpret_cast<const float4*>(lam_im + d0);
    const float lr[4] = { l_re.x, l_re.y, l_re.z, l_re.w };
    const float li[4] = { l_im.x, l_im.y, l_im.z, l_im.w };
    float4 p_re = *reinterpret_cast<const float4*>(pre_re + (size_t)chunk * DDIM + d0);
    float4 p_im = *reinterpret_cast<const float4*>(pre_im + (size_t)chunk * DDIM + d0);
    float hr[4] = { p_re.x, p_re.y, p_re.z, p_re.w };
    float hi[4] = { p_im.x, p_im.y, p_im.z, p_im.w };
    size_t base = ((size_t)b * TSEQ + (size_t)c * CLEN) * DDIM + d0;
    for (int k = 0; k < CLEN; ++k) {
        ushort4 vr = *reinterpret_cast<const ushort4*>(re + base + (size_t)k * DDIM);
        ushort4 vi = *reinterpret_cast<const ushort4*>(im + base + (size_t)k * DDIM);
        const unsigned short* pr = (const unsigned short*)&vr;
        const unsigned short* pi = (const unsigned short*)&vi;
        ushort4 or_, oi_;
        unsigned short* opr = (unsigned short*)&or_;
        unsigned short* opi = (unsigned short*)&oi_;
        #pragma unroll
        for (int j = 0; j < 4; ++j) {
            float br = bf2f(pr[j]), bi = bf2f(pi[j]);
            float nr = fmaf(lr[j], hr[j], fmaf(-li[j], hi[j], br));
            float ni = fmaf(lr[j], hi[j], fmaf(li[j], hr[j], bi));
            hr[j] = nr; hi[j] = ni;
            opr[j] = f2bf(nr); opi[j] = f2bf(ni);
        }
        *reinterpret_cast<ushort4*>(re + base + (size_t)k * DDIM) = or_;
        *reinterpret_cast<ushort4*>(im + base + (size_t)k * DDIM) = oi_;
    }
}

// ---------------- GEMM2 (fused re+im): y = hre*Cre^T + him*(-Cim)^T; u' = u + (y + Dv*z)*sg ----
__global__ __launch_bounds__(256) void gemm2_kernel(
    const unsigned short* __restrict__ hre, const unsigned short* __restrict__ him,
    const unsigned short* __restrict__ wCre, const unsigned short* __restrict__ wCimn,
    const unsigned short* __restrict__ z, const unsigned short* __restrict__ sg,
    const float* __restrict__ Dv, const float* __restrict__ uin, float* __restrict__ uout)
{
    const int n0 = blockIdx.x * 64;
    const int m0 = blockIdx.y * 128;

    __shared__ unsigned short Ar[128 * 64];   // 16 KB
    __shared__ unsigned short Ai[128 * 64];   // 16 KB
    __shared__ unsigned short Cr[64 * 64];    // 8 KB
    __shared__ unsigned short Ci[64 * 64];    // 8 KB

    const int tid = threadIdx.x;
    const int lane = tid & 63;
    const int wid = tid >> 6;
    const int wr = wid >> 1, wc = wid & 1;
    const int lr = lane >> 3;
    const int lc = lane & 7;

    f32x4 acc[4][2] = {};

    for (int ko = 0; ko < 256; ko += 64) {
        #pragma unroll
        for (int it = 0; it < 4; ++it) {
            int s = wid * 4 + it;
            int r = s * 8 + lr;
            int gc = lc ^ (r & 7);
            size_t off = (size_t)(m0 + r) * 256 + ko + gc * 8;
            gload16(hre + off, &Ar[s * 512]);
            gload16(him + off, &Ai[s * 512]);
        }
        #pragma unroll
        for (int it = 0; it < 2; ++it) {
            int s = wid * 2 + it;
            int r = s * 8 + lr;
            int gc = lc ^ (r & 7);
            size_t off = (size_t)(n0 + r) * 256 + ko + gc * 8;
            gload16(wCre + off, &Cr[s * 512]);
            gload16(wCimn + off, &Ci[s * 512]);
        }
        __syncthreads();

        #pragma unroll
        for (int k2 = 0; k2 < 64; k2 += 32) {
            int ac = (k2 >> 3) + (lane >> 4);
            bf16x8 are[4], aim[4];
            #pragma unroll
            for (int mi = 0; mi < 4; ++mi) {
                int arow = wr * 64 + mi * 16 + (lane & 15);
                int idx = arow * 64 + ((ac ^ (arow & 7)) * 8);
                are[mi] = *reinterpret_cast<const bf16x8*>(&Ar[idx]);
                aim[mi] = *reinterpret_cast<const bf16x8*>(&Ai[idx]);
            }
            int br0 = wc * 32 + (lane & 15);
            int br1 = br0 + 16;
            int ib0 = br0 * 64 + ((ac ^ (br0 & 7)) * 8);
            int ib1 = br1 * 64 + ((ac ^ (br1 & 7)) * 8);
            bf16x8 bre0 = *reinterpret_cast<const bf16x8*>(&Cr[ib0]);
            bf16x8 bre1 = *reinterpret_cast<const bf16x8*>(&Cr[ib1]);
            bf16x8 bim0 = *reinterpret_cast<const bf16x8*>(&Ci[ib0]);
            bf16x8 bim1 = *reinterpret_cast<const bf16x8*>(&Ci[ib1]);
            #pragma unroll
            for (int mi = 0; mi < 4; ++mi) {
                acc[mi][0] = __builtin_amdgcn_mfma_f32_16x16x32_bf16(are[mi], bre0, acc[mi][0], 0, 0, 0);
                acc[mi][1] = __builtin_amdgcn_mfma_f32_16x16x32_bf16(are[mi], bre1, acc[mi][1], 0, 0, 0);
                acc[mi][0] = __builtin_amdgcn_mfma_f32_16x16x32_bf16(aim[mi], bim0, acc[mi][0], 0, 0, 0);
                acc[mi][1] = __builtin_amdgcn_mfma_f32_16x16x32_bf16(aim[mi], bim1, acc[mi][1], 0, 0, 0);
            }
        }
        __syncthreads();
    }

    #pragma unroll
    for (int mi = 0; mi < 4; ++mi) {
        #pragma unroll
        for (int ni = 0; ni < 2; ++ni) {
            int col = n0 + wc * 32 + ni * 16 + (lane & 15);
            int mrow = m0 + wr * 64 + mi * 16 + (lane >> 4) * 4;
            float dv = Dv[col];
            #pragma unroll
            for (int j = 0; j < 4; ++j) {
                size_t idx = (size_t)(mrow + j) * 256 + col;
                float y = acc[mi][ni][j];
                float zz = bf2f(z[idx]);
                float s = bf2f(sg[idx]);
                uout[idx] = uin[idx] + (y + dv * zz) * s;
            }
        }
    }
}

extern "C" void kernel_launch(void* const* d_in, const int* in_sizes, int n_in,
                              void* d_out, int out_size, void* d_ws, size_t ws_size,
                              hipStream_t stream) {
    const float* x         = (const float*)d_in[0];
    const float* nu_log    = (const float*)d_in[1];
    const float* theta_log = (const float*)d_in[2];
    const float* gamma_log = (const float*)d_in[3];
    const float* B_re      = (const float*)d_in[4];
    const float* B_im      = (const float*)d_in[5];
    const float* C_re      = (const float*)d_in[6];
    const float* C_im      = (const float*)d_in[7];
    const float* D_vec     = (const float*)d_in[8];
    const float* Wg        = (const float*)d_in[9];
    const float* ln_scale  = (const float*)d_in[10];
    const float* ln_bias   = (const float*)d_in[11];
    float* out = (float*)d_out;

    const size_t MSZ = (size_t)MROWS * DDIM;
    const size_t WSZ = (size_t)NLAYER * DDIM * DDIM;
    const size_t FSZ = (size_t)NBATCH * NCHUNK * DDIM;

    unsigned short* b16 = (unsigned short*)d_ws;
    unsigned short* z     = b16;
    unsigned short* sg    = b16 + MSZ;
    unsigned short* hre   = b16 + 2 * MSZ;
    unsigned short* him   = b16 + 3 * MSZ;
    unsigned short* wBre  = b16 + 4 * MSZ;
    unsigned short* wBim  = wBre + WSZ;
    unsigned short* wWg   = wBim + WSZ;
    unsigned short* wCre  = wWg + WSZ;
    unsigned short* wCimn = wCre + WSZ;
    float* lam_re  = (float*)(wCimn + WSZ);
    float* lam_im  = lam_re + NLAYER * DDIM;
    float* lamC_re = lam_im + NLAYER * DDIM;
    float* lamC_im = lamC_re + NLAYER * DDIM;
    float* fin_re  = lamC_im + NLAYER * DDIM;
    float* fin_im  = fin_re + FSZ;
    float* pre_re  = fin_im + FSZ;
    float* pre_im  = pre_re + FSZ;

    prepack_kernel<<<1024, 256, 0, stream>>>(nu_log, theta_log, gamma_log,
                                             B_re, B_im, C_re, C_im, Wg,
                                             wBre, wBim, wWg, wCre, wCimn,
                                             lam_re, lam_im, lamC_re, lamC_im);

    for (int l = 0; l < NLAYER; ++l) {
        const float* uin = (l == 0) ? x : out;
        const float* lre = lam_re + l * DDIM;
        const float* lim = lam_im + l * DDIM;
        ln_kernel<<<MROWS / 4, 256, 0, stream>>>(uin, z, ln_scale + l * DDIM, ln_bias + l * DDIM);
        gemm1_kernel<<<dim3(4, MROWS / 128), 256, 0, stream>>>(
            z, wBre + l * DDIM * DDIM, wBim + l * DDIM * DDIM, wWg + l * DDIM * DDIM,
            hre, him, sg);
        scan_finals_kernel<<<NBATCH * NCHUNK / 4, 256, 0, stream>>>(hre, him, fin_re, fin_im, lre, lim);
        scan_prefix_kernel<<<NBATCH, 64, 0, stream>>>(fin_re, fin_im, pre_re, pre_im,
                                                      lamC_re + l * DDIM, lamC_im + l * DDIM);
        scan_apply_kernel<<<NBATCH * NCHUNK / 4, 256, 0, stream>>>(hre, him, pre_re, pre_im, lre, lim);
        gemm2_kernel<<<dim3(4, MROWS / 128), 256, 0, stream>>>(
            hre, him, wCre + l * DDIM * DDIM, wCimn + l * DDIM * DDIM,
            z, sg, D_vec + l * DDIM, uin, out);
    }
}

// Round 4
// 386.630 us; speedup vs baseline: 1.1519x; 1.1519x over previous
//
#include <hip/hip_runtime.h>
#include <hip/hip_bf16.h>

#define NLAYER 4
#define DDIM 256
#define TSEQ 4096
#define NBATCH 8
#define MROWS (NBATCH * TSEQ)   // 32768
#define CLEN 32                 // chunk length for parallel scan
#define NCHUNK (TSEQ / CLEN)    // 128

typedef float f32x4 __attribute__((ext_vector_type(4)));
typedef short bf16x8 __attribute__((ext_vector_type(8)));

__device__ __forceinline__ float bf2f(unsigned short u) {
    union { unsigned int i; float f; } v; v.i = ((unsigned int)u) << 16; return v.f;
}
__device__ __forceinline__ unsigned short f2bf(float f) {
    union { float f; unsigned int i; } v; v.f = f;
    unsigned int r = v.i + 0x7fffu + ((v.i >> 16) & 1u);
    return (unsigned short)(r >> 16);
}

// async global->LDS, 16B per lane; lds base must be wave-uniform (HW adds lane*16)
__device__ __forceinline__ void gload16(const unsigned short* g, unsigned short* l) {
    __builtin_amdgcn_global_load_lds(
        (const __attribute__((address_space(1))) unsigned int*)g,
        (__attribute__((address_space(3))) unsigned int*)l, 16, 0, 0);
}

// ---------------- prepack: weights -> bf16 (gamma folded into B, -C_im), lambda, lambda^CLEN ----
__global__ __launch_bounds__(256) void prepack_kernel(
    const float* __restrict__ nu_log, const float* __restrict__ theta_log,
    const float* __restrict__ gamma_log,
    const float* __restrict__ B_re, const float* __restrict__ B_im,
    const float* __restrict__ C_re, const float* __restrict__ C_im,
    const float* __restrict__ Wg,
    unsigned short* __restrict__ wBre, unsigned short* __restrict__ wBim,
    unsigned short* __restrict__ wWg, unsigned short* __restrict__ wCre,
    unsigned short* __restrict__ wCimn,
    float* __restrict__ lam_re, float* __restrict__ lam_im,
    float* __restrict__ lamC_re, float* __restrict__ lamC_im)
{
    int idx = blockIdx.x * 256 + threadIdx.x;
    const int total = NLAYER * DDIM * DDIM;
    if (idx < total) {
        int l = idx >> 16;
        int e = (idx >> 8) & 255;
        float gam = expf(gamma_log[l * DDIM + e]);
        wBre[idx]  = f2bf(B_re[idx] * gam);
        wBim[idx]  = f2bf(B_im[idx] * gam);
        wWg[idx]   = f2bf(Wg[idx]);
        wCre[idx]  = f2bf(C_re[idx]);
        wCimn[idx] = f2bf(-C_im[idx]);
    }
    if (idx < NLAYER * DDIM) {
        float mag = expf(-expf(nu_log[idx]));
        float th  = expf(theta_log[idx]);
        float ar = mag * cosf(th);
        float ai = mag * sinf(th);
        lam_re[idx] = ar;
        lam_im[idx] = ai;
        #pragma unroll
        for (int s = 0; s < 5; ++s) {   // lambda^32
            float nr = ar * ar - ai * ai;
            float ni = 2.0f * ar * ai;
            ar = nr; ai = ni;
        }
        lamC_re[idx] = ar;
        lamC_im[idx] = ai;
    }
}

// ---------------- LayerNorm: one wave per row (D=256), 4 rows/block ----------------
__global__ __launch_bounds__(256) void ln_kernel(
    const float* __restrict__ u, unsigned short* __restrict__ z,
    const float* __restrict__ scale, const float* __restrict__ bias)
{
    int wid = threadIdx.x >> 6;
    int lane = threadIdx.x & 63;
    int row = blockIdx.x * 4 + wid;
    const float4 v = *reinterpret_cast<const float4*>(u + (size_t)row * DDIM + lane * 4);
    float s  = v.x + v.y + v.z + v.w;
    float s2 = v.x * v.x + v.y * v.y + v.z * v.z + v.w * v.w;
    #pragma unroll
    for (int off = 32; off > 0; off >>= 1) {
        s  += __shfl_xor(s, off);
        s2 += __shfl_xor(s2, off);
    }
    float mu  = s * (1.0f / DDIM);
    float var = s2 * (1.0f / DDIM) - mu * mu;
    float inv = rsqrtf(var + 1e-5f);
    float zv[4] = { v.x, v.y, v.z, v.w };
    ushort4 o;
    unsigned short* op = (unsigned short*)&o;
    #pragma unroll
    for (int j = 0; j < 4; ++j) {
        int d = lane * 4 + j;
        op[j] = f2bf((zv[j] - mu) * inv * scale[d] + bias[d]);
    }
    *reinterpret_cast<ushort4*>(z + (size_t)row * DDIM + lane * 4) = o;
}

// ---------------- GEMM1 (fused 3-matrix) + chunk-finals epilogue --------------------------------
// grid (4, 256): n0 = bx*64, m0 = by*128. BM=128, BN=64, BK=64, 4 waves (2x2).
// LDS linear, global source pre-swizzled (chunk ^= row&7), ds_read swizzled to match.
// Epilogue: writes bure/buim/sigmoid(g), then transposes re/im tile into LDS and computes the
// per-chunk (CLEN=32) local-scan finals, stored as float2 {re,im} at fin[(b*256+d)*128 + c].
__global__ __launch_bounds__(256) void gemm1_kernel(
    const unsigned short* __restrict__ z,
    const unsigned short* __restrict__ wBre, const unsigned short* __restrict__ wBim,
    const unsigned short* __restrict__ wWg,
    unsigned short* __restrict__ bure, unsigned short* __restrict__ buim,
    unsigned short* __restrict__ sg,
    const float* __restrict__ lam_re, const float* __restrict__ lam_im,
    float2* __restrict__ fin)
{
    const int n0 = blockIdx.x * 64;
    const int m0 = blockIdx.y * 128;

    __shared__ unsigned short Al[128 * 64];      // 16 KB
    __shared__ unsigned short Wl[3][64 * 64];    // 24 KB

    const int tid = threadIdx.x;
    const int lane = tid & 63;
    const int wid = tid >> 6;
    const int wr = wid >> 1, wc = wid & 1;
    const int lr = lane >> 3;      // row within 8-row segment
    const int lc = lane & 7;       // 16B chunk within row

    f32x4 acc[3][4][2] = {};

    for (int ko = 0; ko < 256; ko += 64) {
        #pragma unroll
        for (int it = 0; it < 4; ++it) {
            int s = wid * 4 + it;
            int r = s * 8 + lr;
            int gc = lc ^ (r & 7);
            gload16(z + (size_t)(m0 + r) * 256 + ko + gc * 8, &Al[s * 512]);
        }
        #pragma unroll
        for (int it = 0; it < 2; ++it) {
            int s = wid * 2 + it;
            int r = s * 8 + lr;
            int gc = lc ^ (r & 7);
            size_t off = (size_t)(n0 + r) * 256 + ko + gc * 8;
            gload16(wBre + off, &Wl[0][s * 512]);
            gload16(wBim + off, &Wl[1][s * 512]);
            gload16(wWg  + off, &Wl[2][s * 512]);
        }
        __syncthreads();

        #pragma unroll
        for (int k2 = 0; k2 < 64; k2 += 32) {
            int ac = (k2 >> 3) + (lane >> 4);
            bf16x8 a[4];
            #pragma unroll
            for (int mi = 0; mi < 4; ++mi) {
                int ar = wr * 64 + mi * 16 + (lane & 15);
                a[mi] = *reinterpret_cast<const bf16x8*>(&Al[ar * 64 + ((ac ^ (ar & 7)) * 8)]);
            }
            int br0 = wc * 32 + (lane & 15);
            int br1 = br0 + 16;
            #pragma unroll
            for (int mat = 0; mat < 3; ++mat) {
                bf16x8 b0 = *reinterpret_cast<const bf16x8*>(&Wl[mat][br0 * 64 + ((ac ^ (br0 & 7)) * 8)]);
                bf16x8 b1 = *reinterpret_cast<const bf16x8*>(&Wl[mat][br1 * 64 + ((ac ^ (br1 & 7)) * 8)]);
                #pragma unroll
                for (int mi = 0; mi < 4; ++mi) {
                    acc[mat][mi][0] = __builtin_amdgcn_mfma_f32_16x16x32_bf16(a[mi], b0, acc[mat][mi][0], 0, 0, 0);
                    acc[mat][mi][1] = __builtin_amdgcn_mfma_f32_16x16x32_bf16(a[mi], b1, acc[mat][mi][1], 0, 0, 0);
                }
            }
        }
        __syncthreads();
    }

    // global writes + LDS transpose of rounded re/im for finals
    unsigned short* Tre = Al;                 // 128x64 u16 = 16 KB
    unsigned short* Tim = &Wl[0][0];          // spans Wl[0..1] = 16 KB
    #pragma unroll
    for (int mat = 0; mat < 3; ++mat) {
        unsigned short* out = (mat == 0) ? bure : ((mat == 1) ? buim : sg);
        #pragma unroll
        for (int mi = 0; mi < 4; ++mi) {
            #pragma unroll
            for (int ni = 0; ni < 2; ++ni) {
                int cl = wc * 32 + ni * 16 + (lane & 15);
                int rl = wr * 64 + mi * 16 + (lane >> 4) * 4;
                #pragma unroll
                for (int j = 0; j < 4; ++j) {
                    float v = acc[mat][mi][ni][j];
                    unsigned short bv;
                    if (mat == 2) { bv = f2bf(1.0f / (1.0f + expf(-v))); }
                    else          { bv = f2bf(v); }
                    out[(size_t)(m0 + rl + j) * 256 + n0 + cl] = bv;
                    if (mat == 0) Tre[(rl + j) * 64 + cl] = bv;
                    if (mat == 1) Tim[(rl + j) * 64 + cl] = bv;
                }
            }
        }
    }
    __syncthreads();
    {
        const int c = tid >> 6;          // local chunk 0..3
        const int col = tid & 63;
        const int dglob = n0 + col;
        const float lr_ = lam_re[dglob], li_ = lam_im[dglob];
        float hr = 0.0f, hi = 0.0f;
        #pragma unroll 8
        for (int k = 0; k < CLEN; ++k) {
            int row = c * 32 + k;
            float br = bf2f(Tre[row * 64 + col]);
            float bi = bf2f(Tim[row * 64 + col]);
            float nr = fmaf(lr_, hr, fmaf(-li_, hi, br));
            float ni = fmaf(lr_, hi, fmaf(li_, hr, bi));
            hr = nr; hi = ni;
        }
        const int b = m0 >> 12;
        const int cglob = ((m0 & 4095) >> 5) + c;
        float2 o; o.x = hr; o.y = hi;
        fin[((size_t)b * 256 + dglob) * 128 + cglob] = o;
    }
}

// ---------------- scan phase B: wave-parallel Kogge-Stone prefix over 128 chunks ---------------
// One 64-lane wave per (b,d); lane c holds chunk finals 2c, 2c+1. 512 blocks x 256 threads.
__global__ __launch_bounds__(256) void scan_prefix_kernel(
    const float2* __restrict__ fin, float2* __restrict__ pre,
    const float* __restrict__ lamC_re, const float* __restrict__ lamC_im)
{
    const int lane = threadIdx.x & 63;
    const int w = blockIdx.x * 4 + (threadIdx.x >> 6);   // 0..2047 = b*256 + d
    const int d = w & 255;
    const float ar = lamC_re[d], ai = lamC_im[d];        // lambda^32
    const float4 f = *reinterpret_cast<const float4*>(fin + (size_t)w * 128 + lane * 2);
    const float f0r = f.x, f0i = f.y, f1r = f.z, f1i = f.w;
    // pair aggregate S = a32*f0 + f1
    float Tr = fmaf(ar, f0r, fmaf(-ai, f0i, f1r));
    float Ti = fmaf(ar, f0i, fmaf(ai, f0r, f1i));
    // A = a64
    float Ar_ = ar * ar - ai * ai;
    float Ai_ = 2.0f * ar * ai;
    #pragma unroll
    for (int s = 1; s < 64; s <<= 1) {
        float ur = __shfl_up(Tr, s, 64);
        float ui = __shfl_up(Ti, s, 64);
        if (lane >= s) {
            Tr = fmaf(Ar_, ur, fmaf(-Ai_, ui, Tr));
            Ti = fmaf(Ar_, ui, fmaf(Ai_, ur, Ti));
        }
        float nr = Ar_ * Ar_ - Ai_ * Ai_;
        float ni = 2.0f * Ar_ * Ai_;
        Ar_ = nr; Ai_ = ni;
    }
    // exclusive: state entering chunk 2c
    float Er = __shfl_up(Tr, 1, 64);
    float Ei = __shfl_up(Ti, 1, 64);
    if (lane == 0) { Er = 0.0f; Ei = 0.0f; }
    // P[2c+1] = a32*P[2c] + f0
    float P1r = fmaf(ar, Er, fmaf(-ai, Ei, f0r));
    float P1i = fmaf(ar, Ei, fmaf(ai, Er, f0i));
    float4 o; o.x = Er; o.y = Ei; o.z = P1r; o.w = P1i;
    *reinterpret_cast<float4*>(pre + (size_t)w * 128 + lane * 2) = o;
}

// ---------------- scan phase C: seeded re-scan, store bf16 in place ----------------------------
__global__ __launch_bounds__(256) void scan_apply_kernel(
    unsigned short* __restrict__ re, unsigned short* __restrict__ im,
    const float2* __restrict__ pre,
    const float* __restrict__ lam_re, const float* __restrict__ lam_im)
{
    const int lane = threadIdx.x & 63;
    const int chunk = blockIdx.x * 4 + (threadIdx.x >> 6);
    const int b = chunk >> 7;
    const int c = chunk & (NCHUNK - 1);
    const int d0 = lane * 4;
    const float4 l_re = *reinterpret_cast<const float4*>(lam_re + d0);
    const float4 l_im = *reinterpret_cast<const float4*>(lam_im + d0);
    const float lr[4] = { l_re.x, l_re.y, l_re.z, l_re.w };
    const float li[4] = { l_im.x, l_im.y, l_im.z, l_im.w };
    float hr[4], hi[4];
    #pragma unroll
    for (int j = 0; j < 4; ++j) {
        float2 p = pre[((size_t)b * 256 + d0 + j) * 128 + c];
        hr[j] = p.x; hi[j] = p.y;
    }
    size_t base = ((size_t)b * TSEQ + (size_t)c * CLEN) * DDIM + d0;
    for (int k = 0; k < CLEN; ++k) {
        ushort4 vr = *reinterpret_cast<const ushort4*>(re + base + (size_t)k * DDIM);
        ushort4 vi = *reinterpret_cast<const ushort4*>(im + base + (size_t)k * DDIM);
        const unsigned short* pr = (const unsigned short*)&vr;
        const unsigned short* pi = (const unsigned short*)&vi;
        ushort4 or_, oi_;
        unsigned short* opr = (unsigned short*)&or_;
        unsigned short* opi = (unsigned short*)&oi_;
        #pragma unroll
        for (int j = 0; j < 4; ++j) {
            float br = bf2f(pr[j]), bi = bf2f(pi[j]);
            float nr = fmaf(lr[j], hr[j], fmaf(-li[j], hi[j], br));
            float ni = fmaf(lr[j], hi[j], fmaf(li[j], hr[j], bi));
            hr[j] = nr; hi[j] = ni;
            opr[j] = f2bf(nr); opi[j] = f2bf(ni);
        }
        *reinterpret_cast<ushort4*>(re + base + (size_t)k * DDIM) = or_;
        *reinterpret_cast<ushort4*>(im + base + (size_t)k * DDIM) = oi_;
    }
}

// ---------------- GEMM2 (fused re+im): y = hre*Cre^T + him*(-Cim)^T; u' = u + (y + Dv*z)*sg ----
__global__ __launch_bounds__(256) void gemm2_kernel(
    const unsigned short* __restrict__ hre, const unsigned short* __restrict__ him,
    const unsigned short* __restrict__ wCre, const unsigned short* __restrict__ wCimn,
    const unsigned short* __restrict__ z, const unsigned short* __restrict__ sg,
    const float* __restrict__ Dv, const float* __restrict__ uin, float* __restrict__ uout)
{
    const int n0 = blockIdx.x * 64;
    const int m0 = blockIdx.y * 128;

    __shared__ unsigned short Ar[128 * 64];   // 16 KB
    __shared__ unsigned short Ai[128 * 64];   // 16 KB
    __shared__ unsigned short Cr[64 * 64];    // 8 KB
    __shared__ unsigned short Ci[64 * 64];    // 8 KB

    const int tid = threadIdx.x;
    const int lane = tid & 63;
    const int wid = tid >> 6;
    const int wr = wid >> 1, wc = wid & 1;
    const int lr = lane >> 3;
    const int lc = lane & 7;

    f32x4 acc[4][2] = {};

    for (int ko = 0; ko < 256; ko += 64) {
        #pragma unroll
        for (int it = 0; it < 4; ++it) {
            int s = wid * 4 + it;
            int r = s * 8 + lr;
            int gc = lc ^ (r & 7);
            size_t off = (size_t)(m0 + r) * 256 + ko + gc * 8;
            gload16(hre + off, &Ar[s * 512]);
            gload16(him + off, &Ai[s * 512]);
        }
        #pragma unroll
        for (int it = 0; it < 2; ++it) {
            int s = wid * 2 + it;
            int r = s * 8 + lr;
            int gc = lc ^ (r & 7);
            size_t off = (size_t)(n0 + r) * 256 + ko + gc * 8;
            gload16(wCre + off, &Cr[s * 512]);
            gload16(wCimn + off, &Ci[s * 512]);
        }
        __syncthreads();

        #pragma unroll
        for (int k2 = 0; k2 < 64; k2 += 32) {
            int ac = (k2 >> 3) + (lane >> 4);
            bf16x8 are[4], aim[4];
            #pragma unroll
            for (int mi = 0; mi < 4; ++mi) {
                int arow = wr * 64 + mi * 16 + (lane & 15);
                int idx = arow * 64 + ((ac ^ (arow & 7)) * 8);
                are[mi] = *reinterpret_cast<const bf16x8*>(&Ar[idx]);
                aim[mi] = *reinterpret_cast<const bf16x8*>(&Ai[idx]);
            }
            int br0 = wc * 32 + (lane & 15);
            int br1 = br0 + 16;
            int ib0 = br0 * 64 + ((ac ^ (br0 & 7)) * 8);
            int ib1 = br1 * 64 + ((ac ^ (br1 & 7)) * 8);
            bf16x8 bre0 = *reinterpret_cast<const bf16x8*>(&Cr[ib0]);
            bf16x8 bre1 = *reinterpret_cast<const bf16x8*>(&Cr[ib1]);
            bf16x8 bim0 = *reinterpret_cast<const bf16x8*>(&Ci[ib0]);
            bf16x8 bim1 = *reinterpret_cast<const bf16x8*>(&Ci[ib1]);
            #pragma unroll
            for (int mi = 0; mi < 4; ++mi) {
                acc[mi][0] = __builtin_amdgcn_mfma_f32_16x16x32_bf16(are[mi], bre0, acc[mi][0], 0, 0, 0);
                acc[mi][1] = __builtin_amdgcn_mfma_f32_16x16x32_bf16(are[mi], bre1, acc[mi][1], 0, 0, 0);
                acc[mi][0] = __builtin_amdgcn_mfma_f32_16x16x32_bf16(aim[mi], bim0, acc[mi][0], 0, 0, 0);
                acc[mi][1] = __builtin_amdgcn_mfma_f32_16x16x32_bf16(aim[mi], bim1, acc[mi][1], 0, 0, 0);
            }
        }
        __syncthreads();
    }

    #pragma unroll
    for (int mi = 0; mi < 4; ++mi) {
        #pragma unroll
        for (int ni = 0; ni < 2; ++ni) {
            int col = n0 + wc * 32 + ni * 16 + (lane & 15);
            int mrow = m0 + wr * 64 + mi * 16 + (lane >> 4) * 4;
            float dv = Dv[col];
            #pragma unroll
            for (int j = 0; j < 4; ++j) {
                size_t idx = (size_t)(mrow + j) * 256 + col;
                float y = acc[mi][ni][j];
                float zz = bf2f(z[idx]);
                float s = bf2f(sg[idx]);
                uout[idx] = uin[idx] + (y + dv * zz) * s;
            }
        }
    }
}

extern "C" void kernel_launch(void* const* d_in, const int* in_sizes, int n_in,
                              void* d_out, int out_size, void* d_ws, size_t ws_size,
                              hipStream_t stream) {
    const float* x         = (const float*)d_in[0];
    const float* nu_log    = (const float*)d_in[1];
    const float* theta_log = (const float*)d_in[2];
    const float* gamma_log = (const float*)d_in[3];
    const float* B_re      = (const float*)d_in[4];
    const float* B_im      = (const float*)d_in[5];
    const float* C_re      = (const float*)d_in[6];
    const float* C_im      = (const float*)d_in[7];
    const float* D_vec     = (const float*)d_in[8];
    const float* Wg        = (const float*)d_in[9];
    const float* ln_scale  = (const float*)d_in[10];
    const float* ln_bias   = (const float*)d_in[11];
    float* out = (float*)d_out;

    const size_t MSZ = (size_t)MROWS * DDIM;
    const size_t WSZ = (size_t)NLAYER * DDIM * DDIM;
    const size_t FSZ = (size_t)NBATCH * DDIM * NCHUNK;   // 262144 float2

    unsigned short* b16 = (unsigned short*)d_ws;
    unsigned short* z     = b16;
    unsigned short* sg    = b16 + MSZ;
    unsigned short* hre   = b16 + 2 * MSZ;
    unsigned short* him   = b16 + 3 * MSZ;
    unsigned short* wBre  = b16 + 4 * MSZ;
    unsigned short* wBim  = wBre + WSZ;
    unsigned short* wWg   = wBim + WSZ;
    unsigned short* wCre  = wWg + WSZ;
    unsigned short* wCimn = wCre + WSZ;
    float* lam_re  = (float*)(wCimn + WSZ);
    float* lam_im  = lam_re + NLAYER * DDIM;
    float* lamC_re = lam_im + NLAYER * DDIM;
    float* lamC_im = lamC_re + NLAYER * DDIM;
    float2* fin = (float2*)(lamC_im + NLAYER * DDIM);
    float2* pre = fin + FSZ;

    prepack_kernel<<<1024, 256, 0, stream>>>(nu_log, theta_log, gamma_log,
                                             B_re, B_im, C_re, C_im, Wg,
                                             wBre, wBim, wWg, wCre, wCimn,
                                             lam_re, lam_im, lamC_re, lamC_im);

    for (int l = 0; l < NLAYER; ++l) {
        const float* uin = (l == 0) ? x : out;
        const float* lre = lam_re + l * DDIM;
        const float* lim = lam_im + l * DDIM;
        ln_kernel<<<MROWS / 4, 256, 0, stream>>>(uin, z, ln_scale + l * DDIM, ln_bias + l * DDIM);
        gemm1_kernel<<<dim3(4, MROWS / 128), 256, 0, stream>>>(
            z, wBre + l * DDIM * DDIM, wBim + l * DDIM * DDIM, wWg + l * DDIM * DDIM,
            hre, him, sg, lre, lim, fin);
        scan_prefix_kernel<<<512, 256, 0, stream>>>(fin, pre,
                                                    lamC_re + l * DDIM, lamC_im + l * DDIM);
        scan_apply_kernel<<<NBATCH * NCHUNK / 4, 256, 0, stream>>>(hre, him, pre, lre, lim);
        gemm2_kernel<<<dim3(4, MROWS / 128), 256, 0, stream>>>(
            hre, him, wCre + l * DDIM * DDIM, wCimn + l * DDIM * DDIM,
            z, sg, D_vec + l * DDIM, uin, out);
    }
}